// Round 4
// baseline (258.528 us; speedup 1.0000x reference)
//
#include <hip/hip_runtime.h>

#define WIDTH  1024
#define HEIGHT 1024
#define WALK   8            // rows marched per block; HEIGHT % WALK == 0

typedef float vfloat4 __attribute__((ext_vector_type(4)));

__global__ __launch_bounds__(256, 4) void fdtd_kernel(
    const float* __restrict__ u1,
    const float* __restrict__ u0,
    const float* __restrict__ j2,
    const float* __restrict__ j0,
    float* __restrict__ out,
    int chunk)                              // gridDim.x / 8 (0 => no swizzle)
{
    // XCD-aware chunked swizzle: consecutive y-blocks (sharing halo rows) on one XCD's L2.
    const int bid = blockIdx.x;
    const int swz = chunk ? ((bid & 7) * chunk + (bid >> 3)) : bid;

    const int y0   = swz * WALK;            // first computed global row
    const int iy   = y0 & (HEIGHT - 1);     // row within image (blocks never straddle images)
    const int x0   = threadIdx.x << 2;      // 4 floats/thread: 256 threads cover the 1024-row
    const int lane = threadIdx.x & 63;
    const long base = (long)y0 * WIDTH + x0;
    const vfloat4 zero = {0.f, 0.f, 0.f, 0.f};

    // ---- rolling u1 window: w0=up, w1=center, w2=down ----
    vfloat4 w0, w1, w2;
    w0 = (iy > 0) ? *(const vfloat4*)(u1 + base - WIDTH) : zero;
    w1 = *(const vfloat4*)(u1 + base);
    w2 = *(const vfloat4*)(u1 + base + WIDTH);          // iy+1 <= HEIGHT-WALK+1, always valid

    // ---- double-buffered streams + wave-edge scalars (index is compile-time under unroll) ----
    vfloat4 a0b[2], v2b[2], v0b[2];
    float   elb[2], erb[2];
    a0b[0] = __builtin_nontemporal_load((const vfloat4*)(u0 + base));
    v2b[0] = __builtin_nontemporal_load((const vfloat4*)(j2 + base));
    v0b[0] = __builtin_nontemporal_load((const vfloat4*)(j0 + base));
    elb[0] = (lane == 0  && x0 > 0)         ? u1[base - 1] : 0.f;
    erb[0] = (lane == 63 && x0 + 4 < WIDTH) ? u1[base + 4] : 0.f;

#pragma unroll
    for (int s = 0; s < WALK; ++s) {
        const int cur = s & 1, nxt = cur ^ 1;

        // ---- issue step s+1's loads BEFORE consuming step s's (continuous pipeline) ----
        vfloat4 nx = zero;
        if (s + 1 < WALK) {
            const long bn = base + (long)(s + 1) * WIDTH;
            a0b[nxt] = __builtin_nontemporal_load((const vfloat4*)(u0 + bn));
            v2b[nxt] = __builtin_nontemporal_load((const vfloat4*)(j2 + bn));
            v0b[nxt] = __builtin_nontemporal_load((const vfloat4*)(j0 + bn));
            elb[nxt] = (lane == 0  && x0 > 0)         ? u1[bn - 1] : 0.f;
            erb[nxt] = (lane == 63 && x0 + 4 < WIDTH) ? u1[bn + 4] : 0.f;
            if (s + 2 < WALK || iy + WALK < HEIGHT)     // next dn row (bottom halo guard)
                nx = *(const vfloat4*)(u1 + base + (long)(s + 2) * WIDTH);
        }

        // ---- compute row s from the register window ----
        float lf = __shfl_up(w1.w, 1);
        if (lane == 0)  lf = elb[cur];
        float rt = __shfl_down(w1.x, 1);
        if (lane == 63) rt = erb[cur];

        const vfloat4 a0 = a0b[cur], v2 = v2b[cur], v0 = v0b[cur];
        vfloat4 o;
        o.x = 2.0f * w1.x - a0.x + 0.25f * (w0.x + w2.x + lf   + w1.y - 4.0f * w1.x)
            - 0.0025f * (v2.x - v0.x);
        o.y = 2.0f * w1.y - a0.y + 0.25f * (w0.y + w2.y + w1.x + w1.z - 4.0f * w1.y)
            - 0.0025f * (v2.y - v0.y);
        o.z = 2.0f * w1.z - a0.z + 0.25f * (w0.z + w2.z + w1.y + w1.w - 4.0f * w1.z)
            - 0.0025f * (v2.z - v0.z);
        o.w = 2.0f * w1.w - a0.w + 0.25f * (w0.w + w2.w + w1.z + rt   - 4.0f * w1.w)
            - 0.0025f * (v2.w - v0.w);
        __builtin_nontemporal_store(o, (vfloat4*)(out + base + (long)s * WIDTH));

        // rotate window
        w0 = w1; w1 = w2; w2 = nx;
    }
}

extern "C" void kernel_launch(void* const* d_in, const int* in_sizes, int n_in,
                              void* d_out, int out_size, void* d_ws, size_t ws_size,
                              hipStream_t stream) {
    const float* u1 = (const float*)d_in[0];
    const float* u0 = (const float*)d_in[1];
    const float* j2 = (const float*)d_in[2];
    const float* j0 = (const float*)d_in[3];
    float* out = (float*)d_out;

    const int nrows   = out_size / WIDTH;   // B*H = 16384 (out_size is element count)
    const int nblocks = nrows / WALK;       // 2048 = exactly 8 blocks/CU, one generation
    const int chunk   = (nblocks % 8 == 0) ? (nblocks >> 3) : 0;

    dim3 block(WIDTH / 4);                  // 256 threads: one full row per step
    dim3 grid(nblocks);
    fdtd_kernel<<<grid, block, 0, stream>>>(u1, u0, j2, j0, out, chunk);
}

// Round 5
// 249.290 us; speedup vs baseline: 1.0371x; 1.0371x over previous
//
#include <hip/hip_runtime.h>

#define WIDTH  1024
#define HEIGHT 1024
#define R      4            // rows per block; HEIGHT % R == 0 so blocks never straddle images

typedef float vfloat4 __attribute__((ext_vector_type(4)));

__global__ __launch_bounds__(256, 2) void fdtd_kernel(   // min 2 waves/EU -> 256 VGPR cap
    const float* __restrict__ u1,
    const float* __restrict__ u0,
    const float* __restrict__ j2,
    const float* __restrict__ j0,
    float* __restrict__ out,
    int chunk)                              // gridDim.x / 8 (0 => no swizzle)
{
    // XCD-aware chunked swizzle: consecutive row-blocks share an XCD's L2.
    const int bid = blockIdx.x;
    const int swz = chunk ? ((bid & 7) * chunk + (bid >> 3)) : bid;

    const int y0 = swz * R;                 // first computed global row
    const int iy = y0 & (HEIGHT - 1);       // row within image (block fully inside one image)
    const int x0 = threadIdx.x << 2;        // 4 floats/thread, full 1024-wide row per block
    const long base = (long)y0 * WIDTH + x0;

    // ---- branch-free halo addressing: clamped (in-bounds) offsets + 0/1 masks ----
    const long  upOff  = (iy > 0)          ? -(long)WIDTH     : 0;                    // s_cselect
    const long  dnOff  = (iy + R < HEIGHT) ? (long)R * WIDTH  : (long)(R - 1) * WIDTH;
    const float upMask = (iy > 0)          ? 1.0f : 0.0f;
    const float dnMask = (iy + R < HEIGHT) ? 1.0f : 0.0f;
    const long  lfOff  = (x0 > 0)          ? -1L : 0L;                                // v_cndmask
    const long  rtOff  = (x0 + 4 < WIDTH)  ?  4L : 3L;
    const float lfMask = (x0 > 0)          ? 1.0f : 0.0f;
    const float rtMask = (x0 + 4 < WIDTH)  ? 1.0f : 0.0f;

    // ---- phase 1: ONE basic block, every load unconditional ----
    vfloat4 ctop, c[R], cbot, a0[R], v2[R], v0[R];
    float lf[R], rt[R];

    ctop = *(const vfloat4*)(u1 + base + upOff);
#pragma unroll
    for (int r = 0; r < R; ++r)
        c[r] = *(const vfloat4*)(u1 + base + (long)r * WIDTH);
    cbot = *(const vfloat4*)(u1 + base + dnOff);

#pragma unroll
    for (int r = 0; r < R; ++r) {
        const long b = base + (long)r * WIDTH;
        lf[r] = u1[b + lfOff];              // L1 hit (same rows as c[r])
        rt[r] = u1[b + rtOff];
        a0[r] = __builtin_nontemporal_load((const vfloat4*)(u0 + b));
        v2[r] = __builtin_nontemporal_load((const vfloat4*)(j2 + b));
        v0[r] = __builtin_nontemporal_load((const vfloat4*)(j0 + b));
    }

    // Single-basic-block fence: nothing above may sink below, nothing below may hoist above.
    // All ~19 vec4 + 8 dword results must be live here -> ~19 requests in flight per wave.
    __builtin_amdgcn_sched_barrier(0);

    // ---- phase 2: compute + store ----
#pragma unroll
    for (int r = 0; r < R; ++r) {
        const vfloat4 up = (r == 0)     ? (vfloat4)(ctop * upMask) : c[r - 1];
        const vfloat4 dn = (r == R - 1) ? (vfloat4)(cbot * dnMask) : c[r + 1];
        const vfloat4 ce = c[r];
        const float lfv = lf[r] * lfMask;
        const float rtv = rt[r] * rtMask;

        vfloat4 o;
        o.x = 2.0f * ce.x - a0[r].x + 0.25f * (up.x + dn.x + lfv  + ce.y - 4.0f * ce.x)
            - 0.0025f * (v2[r].x - v0[r].x);
        o.y = 2.0f * ce.y - a0[r].y + 0.25f * (up.y + dn.y + ce.x + ce.z - 4.0f * ce.y)
            - 0.0025f * (v2[r].y - v0[r].y);
        o.z = 2.0f * ce.z - a0[r].z + 0.25f * (up.z + dn.z + ce.y + ce.w - 4.0f * ce.z)
            - 0.0025f * (v2[r].z - v0[r].z);
        o.w = 2.0f * ce.w - a0[r].w + 0.25f * (up.w + dn.w + ce.z + rtv  - 4.0f * ce.w)
            - 0.0025f * (v2[r].w - v0[r].w);
        __builtin_nontemporal_store(o, (vfloat4*)(out + base + (long)r * WIDTH));
    }
}

extern "C" void kernel_launch(void* const* d_in, const int* in_sizes, int n_in,
                              void* d_out, int out_size, void* d_ws, size_t ws_size,
                              hipStream_t stream) {
    const float* u1 = (const float*)d_in[0];
    const float* u0 = (const float*)d_in[1];
    const float* j2 = (const float*)d_in[2];
    const float* j0 = (const float*)d_in[3];
    float* out = (float*)d_out;

    const int nrows   = out_size / WIDTH;   // B*H = 16384 (out_size is element count)
    const int nblocks = nrows / R;          // 4096
    const int chunk   = (nblocks % 8 == 0) ? (nblocks >> 3) : 0;

    dim3 block(WIDTH / 4);                  // 256 threads: one full row per block-row
    dim3 grid(nblocks);
    fdtd_kernel<<<grid, block, 0, stream>>>(u1, u0, j2, j0, out, chunk);
}